// Round 2
// baseline (206.145 us; speedup 1.0000x reference)
//
#include <hip/hip_runtime.h>

#define IN_F   1024
#define OUT_F  64
#define INTER  32
#define BATCH  512
#define NCOL   (OUT_F * INTER)   // 2048
#define OUT_W  (IN_F + OUT_F)    // 1088

// ---------------- GEMM: M[512][2048] = x[512][1024] @ T[1024][2048] ----------------
// 32x32 tiles, 2x2 microtile -> 1024 blocks (4/CU, 16 waves/CU).
#define BK  32
#define LDP 36   // pad: 16B-aligned float4 writes, <=2-way bank conflicts (free)

__global__ __launch_bounds__(256, 4) void gemm_kernel(const float* __restrict__ x,
                                                      const float* __restrict__ T,
                                                      float* __restrict__ M) {
    __shared__ float As[BK][LDP];   // A transposed: As[k][row]
    __shared__ float Bs[BK][LDP];   // Bs[k][col]

    const int bx = blockIdx.x;      // col tile 0..63
    const int by = blockIdx.y;      // row tile 0..15
    const int tid = threadIdx.x;
    const int tx = tid & 15;        // microtile col pair
    const int ty = tid >> 4;        // microtile row pair

    const int lrow = tid >> 3;      // 0..31 (A row / B k-row)
    const int lk4  = (tid & 7) * 4; // 0,4,...,28

    const float* xp = x + (by * 32 + lrow) * IN_F + lk4;
    const float* Tp = T + lrow * NCOL + bx * 32 + lk4;

    float acc00 = 0.f, acc01 = 0.f, acc10 = 0.f, acc11 = 0.f;

    for (int k0 = 0; k0 < IN_F; k0 += BK) {
        const float4 a4 = *(const float4*)(xp + k0);
        const float4 b4 = *(const float4*)(Tp + (size_t)k0 * NCOL);
        As[lk4 + 0][lrow] = a4.x;
        As[lk4 + 1][lrow] = a4.y;
        As[lk4 + 2][lrow] = a4.z;
        As[lk4 + 3][lrow] = a4.w;
        *(float4*)&Bs[lrow][lk4] = b4;
        __syncthreads();

        #pragma unroll
        for (int k = 0; k < BK; ++k) {
            const float2 a2 = *(const float2*)&As[k][ty * 2];
            const float2 b2 = *(const float2*)&Bs[k][tx * 2];
            acc00 += a2.x * b2.x;
            acc01 += a2.x * b2.y;
            acc10 += a2.y * b2.x;
            acc11 += a2.y * b2.y;
        }
        __syncthreads();
    }

    float* Mp = M + (by * 32 + ty * 2) * NCOL + bx * 32 + tx * 2;
    *(float2*)Mp          = make_float2(acc00, acc01);
    *(float2*)(Mp + NCOL) = make_float2(acc10, acc11);
}

// ---------------- Pairwise L1 + exp, partial over b, atomic accumulate ----------------
// grid (8 a-chunks, 64 o, 4 b-slices), block 256 (4 waves). Wave w covers 32 b's.
// 8192 waves total = 32 waves/CU (full occupancy). One atomic per (a,o) per block.
__global__ __launch_bounds__(256, 8) void pairwise_kernel(const float* __restrict__ M,
                                                          float* __restrict__ out) {
    const int o    = blockIdx.y;
    const int a0   = blockIdx.x * 64;
    const int bs   = blockIdx.z;
    const int lane = threadIdx.x & 63;
    const int wave = threadIdx.x >> 6;
    const int a    = a0 + lane;

    float ma[INTER];
    {
        const float* pa = M + a * NCOL + o * INTER;
        #pragma unroll
        for (int k = 0; k < INTER; k += 4) {
            const float4 v = *(const float4*)(pa + k);
            ma[k] = v.x; ma[k + 1] = v.y; ma[k + 2] = v.z; ma[k + 3] = v.w;
        }
    }

    float f = 0.f;
    const float* pb = M + (bs * 128 + wave * 32) * NCOL + o * INTER;
    #pragma unroll 2
    for (int b = 0; b < 32; ++b) {
        float d0 = 0.f, d1 = 0.f, d2 = 0.f, d3 = 0.f;  // 4 accs break dep chain
        #pragma unroll
        for (int k = 0; k < INTER; k += 4) {
            const float4 mb = *(const float4*)(pb + k);   // wave-uniform -> broadcast
            d0 += fabsf(ma[k]     - mb.x);
            d1 += fabsf(ma[k + 1] - mb.y);
            d2 += fabsf(ma[k + 2] - mb.z);
            d3 += fabsf(ma[k + 3] - mb.w);
        }
        f += __expf(-((d0 + d1) + (d2 + d3)));
        pb += NCOL;
    }

    __shared__ float part[4][64];
    part[wave][lane] = f;
    __syncthreads();
    if (wave == 0) {
        const float s = part[0][lane] + part[1][lane] + part[2][lane] + part[3][lane];
        atomicAdd(&out[a * OUT_W + IN_F + o], s);
    }
}

// ---------------- Copy x into out[:, 0:1024] and zero out[:, 1024:1088] ----------------
__global__ __launch_bounds__(256) void copy_x_kernel(const float* __restrict__ x,
                                                     float* __restrict__ out) {
    const int r = blockIdx.x;       // row
    const int c = threadIdx.x;      // float4 index
    *(float4*)(out + r * OUT_W + c * 4) = ((const float4*)(x + r * IN_F))[c];
    if (c < OUT_F / 4)
        *(float4*)(out + r * OUT_W + IN_F + c * 4) = make_float4(0.f, 0.f, 0.f, 0.f);
}

extern "C" void kernel_launch(void* const* d_in, const int* in_sizes, int n_in,
                              void* d_out, int out_size, void* d_ws, size_t ws_size,
                              hipStream_t stream) {
    const float* x = (const float*)d_in[0];   // [512,1024]
    const float* T = (const float*)d_in[1];   // [1024,2048] row-major
    float* out = (float*)d_out;               // [512,1088]
    float* M   = (float*)d_ws;                // [512,2048] scratch (4 MB)

    copy_x_kernel<<<BATCH, 256, 0, stream>>>(x, out);   // also zero-inits feature cols

    dim3 ggrid(NCOL / 32, BATCH / 32);        // 64 x 16 = 1024 blocks
    gemm_kernel<<<ggrid, 256, 0, stream>>>(x, T, M);

    dim3 pgrid(BATCH / 64, OUT_F, 4);         // 8 x 64 x 4 = 2048 blocks
    pairwise_kernel<<<pgrid, 256, 0, stream>>>(M, out);
}

// Round 3
// 146.691 us; speedup vs baseline: 1.4053x; 1.4053x over previous
//
#include <hip/hip_runtime.h>
#include <hip/hip_bf16.h>

#define IN_F   1024
#define OUT_F  64
#define INTER  32
#define BATCH  512
#define NCOL   2048              // OUT_F * INTER
#define OUT_W  1088              // IN_F + OUT_F

typedef short bf16x8 __attribute__((ext_vector_type(8)));  // 8 bf16 (4 VGPRs)
typedef float f32x4  __attribute__((ext_vector_type(4)));  // 4 fp32 acc

__device__ __forceinline__ unsigned short f2bf(float v) {
    __hip_bfloat16 h = __float2bfloat16(v);
    return *reinterpret_cast<unsigned short*>(&h);
}

// ---------------- Prep: copy x -> out, cast x -> xb (bf16), transpose T -> Bt[n][k] bf16 ----
// blocks [0,512): row r of x: copy to out + cast to xb.
// blocks [512,1024): 64x64 tile transpose of T (1024x2048 fp32, k-major) -> Bt (2048x1024 bf16).
__global__ __launch_bounds__(256) void prep_kernel(const float* __restrict__ x,
                                                   const float* __restrict__ T,
                                                   float* __restrict__ out,
                                                   unsigned short* __restrict__ xb,
                                                   unsigned short* __restrict__ Bt) {
    const int tid = threadIdx.x;
    if (blockIdx.x < BATCH) {
        const int r = blockIdx.x;
        const float4 v = ((const float4*)(x + (size_t)r * IN_F))[tid];
        *(float4*)(out + (size_t)r * OUT_W + tid * 4) = v;
        unsigned short h[4] = {f2bf(v.x), f2bf(v.y), f2bf(v.z), f2bf(v.w)};
        *(uint2*)(xb + (size_t)r * IN_F + tid * 4) = *(uint2*)h;
    } else {
        __shared__ unsigned short ldsT[64][72];   // [n][k], row stride 144B (16B-aligned)
        const int bid = blockIdx.x - BATCH;
        const int n0 = (bid & 31) * 64;
        const int k0 = (bid >> 5) * 64;
        // phase 1: read T coalesced along n, each thread holds 16 k's at fixed n
        const int nl = tid & 63;
        const int kc = (tid >> 6) * 16;
        unsigned short u[16];
        #pragma unroll
        for (int j = 0; j < 16; ++j)
            u[j] = f2bf(T[(size_t)(k0 + kc + j) * NCOL + n0 + nl]);
        *(uint4*)&ldsT[nl][kc]     = *(uint4*)&u[0];
        *(uint4*)&ldsT[nl][kc + 8] = *(uint4*)&u[8];
        __syncthreads();
        // phase 2: write Bt coalesced along k
        const int n2  = tid >> 2;
        const int kc2 = (tid & 3) * 16;
        uint4 a = *(uint4*)&ldsT[n2][kc2];
        uint4 b = *(uint4*)&ldsT[n2][kc2 + 8];
        unsigned short* dst = Bt + (size_t)(n0 + n2) * IN_F + k0 + kc2;
        *(uint4*)dst       = a;
        *(uint4*)(dst + 8) = b;
    }
}

// ---------------- GEMM (bf16 MFMA, no LDS, no barriers) ----------------
// Wave computes a 16(m) x 32(n) strip via 2x mfma_f32_16x16x32_bf16 per K-step.
// Fragments load directly from global: A[m=lane&15][k=quad*8+j] from xb rows,
// B[k=quad*8+j][n=lane&15] from Bt rows (n-major). Output to Mt[o][b][k] fp32.
__global__ __launch_bounds__(256) void gemm_kernel(const unsigned short* __restrict__ xb,
                                                   const unsigned short* __restrict__ Bt,
                                                   float* __restrict__ Mt) {
    const int tid  = threadIdx.x;
    const int wave = tid >> 6, lane = tid & 63;
    const int quad = lane >> 4, lr = lane & 15;
    const int m0 = (blockIdx.y * 4 + wave) * 16;
    const int n0 = blockIdx.x * 32;

    const unsigned short* pA  = xb + (size_t)(m0 + lr) * IN_F + quad * 8;
    const unsigned short* pB0 = Bt + (size_t)(n0 + lr) * IN_F + quad * 8;
    const unsigned short* pB1 = pB0 + 16 * IN_F;

    f32x4 acc0 = {0.f, 0.f, 0.f, 0.f};
    f32x4 acc1 = {0.f, 0.f, 0.f, 0.f};
    #pragma unroll 8
    for (int k0 = 0; k0 < IN_F; k0 += 32) {
        bf16x8 a  = *(const bf16x8*)(pA + k0);
        bf16x8 b0 = *(const bf16x8*)(pB0 + k0);
        bf16x8 b1 = *(const bf16x8*)(pB1 + k0);
        acc0 = __builtin_amdgcn_mfma_f32_16x16x32_bf16(a, b0, acc0, 0, 0, 0);
        acc1 = __builtin_amdgcn_mfma_f32_16x16x32_bf16(a, b1, acc1, 0, 0, 0);
    }
    // C/D layout: col = lane&15, row = quad*4 + r (verified m89/m91).
    // cols n0..n0+15 -> o = n0>>5, k = lr; cols n0+16..n0+31 -> k = 16+lr.
    float* base = Mt + (size_t)(n0 >> 5) * (BATCH * INTER) + (size_t)(m0 + quad * 4) * INTER;
    #pragma unroll
    for (int r = 0; r < 4; ++r) {
        base[r * INTER + lr]      = acc0[r];
        base[r * INTER + 16 + lr] = acc1[r];
    }
}

// ---------------- Pairwise L1 + exp + reduce over b ----------------
// Mt[o][b][k]: per-o slab is 64KB contiguous -> no L2 set aliasing.
// grid (8 a-chunks, 64 o), block 256 (4 waves); wave w reduces b in [w*128,(w+1)*128).
__global__ __launch_bounds__(256) void pairwise_kernel(const float* __restrict__ Mt,
                                                       float* __restrict__ out) {
    const int o    = blockIdx.y;
    const int a0   = blockIdx.x * 64;
    const int lane = threadIdx.x & 63;
    const int wave = threadIdx.x >> 6;
    const int a    = a0 + lane;
    const float* slab = Mt + (size_t)o * (BATCH * INTER);

    float ma[INTER];
    {
        const float* pa = slab + (size_t)a * INTER;
        #pragma unroll
        for (int k = 0; k < INTER; k += 4) {
            const float4 v = *(const float4*)(pa + k);
            ma[k] = v.x; ma[k + 1] = v.y; ma[k + 2] = v.z; ma[k + 3] = v.w;
        }
    }

    float f = 0.f;
    const float* pb = slab + (size_t)(wave * 128) * INTER;
    #pragma unroll 2
    for (int b = 0; b < 128; ++b) {
        float d0 = 0.f, d1 = 0.f, d2 = 0.f, d3 = 0.f;  // 4 accs break dep chain
        #pragma unroll
        for (int k = 0; k < INTER; k += 4) {
            const float4 mb = *(const float4*)(pb + k);   // wave-uniform
            d0 += fabsf(ma[k]     - mb.x);
            d1 += fabsf(ma[k + 1] - mb.y);
            d2 += fabsf(ma[k + 2] - mb.z);
            d3 += fabsf(ma[k + 3] - mb.w);
        }
        f += __expf(-((d0 + d1) + (d2 + d3)));
        pb += INTER;
    }

    __shared__ float part[4][64];
    part[wave][lane] = f;
    __syncthreads();
    if (wave == 0) {
        const float s = part[0][lane] + part[1][lane] + part[2][lane] + part[3][lane];
        out[(size_t)a * OUT_W + IN_F + o] = s;
    }
}

extern "C" void kernel_launch(void* const* d_in, const int* in_sizes, int n_in,
                              void* d_out, int out_size, void* d_ws, size_t ws_size,
                              hipStream_t stream) {
    const float* x = (const float*)d_in[0];   // [512,1024] fp32
    const float* T = (const float*)d_in[1];   // [1024,2048] fp32 row-major (k-major)
    float* out = (float*)d_out;               // [512,1088] fp32

    // ws layout: xb (1MB) | Bt (4MB) | Mt (4MB) = 9MB
    unsigned short* xb = (unsigned short*)d_ws;                          // [512][1024] bf16
    unsigned short* Bt = (unsigned short*)((char*)d_ws + (1u << 20));    // [2048][1024] bf16
    float*          Mt = (float*)((char*)d_ws + (5u << 20));             // [64][512][32] fp32

    prep_kernel<<<1024, 256, 0, stream>>>(x, T, out, xb, Bt);

    dim3 ggrid(NCOL / 32, BATCH / 64);        // 64 x 8 = 512 blocks, wave-per-16-rows
    gemm_kernel<<<ggrid, 256, 0, stream>>>(xb, Bt, Mt);

    dim3 pgrid(BATCH / 64, OUT_F);            // 8 x 64 = 512 blocks
    pairwise_kernel<<<pgrid, 256, 0, stream>>>(Mt, out);
}